// Round 14
// baseline (346.805 us; speedup 1.0000x reference)
//
#include <hip/hip_runtime.h>
#include <cstdint>
#include <cstddef>

#define N_NODES 50000
#define N_EDGES 800000
#define HDIM    256
#define NREL    8
#define NSEG    (N_NODES * NREL)      // 400000
#define KDIM    (NREL * HDIM + HDIM)  // 2304 GEMM K: [mean slices | node_states]
#define KA      (NREL * HDIM)         // 2048 cols with aggregated data
#define LN_EPSF 1e-5f

#define SCAN_CHUNK 1024
#define SCAN_NB    ((NSEG + SCAN_CHUNK - 1) / SCAN_CHUNK)   // 391

#define AG_SLICES 8     // 32-col slices; slice -> XCD via blockIdx.x (linear rr)
#define AG_NPB    256   // nodes per aggregate block

using short8  = __attribute__((ext_vector_type(8))) short;
using ushort8 = __attribute__((ext_vector_type(8))) unsigned short;
using float4v = __attribute__((ext_vector_type(4))) float;

static __device__ __forceinline__ unsigned short f2bf(float f) {
    union { float f; uint32_t i; } v; v.f = f;
    uint32_t r = v.i + 0x7FFFu + ((v.i >> 16) & 1u);   // round-to-nearest-even
    return (unsigned short)(r >> 16);
}
static __device__ __forceinline__ float bf2f(unsigned short u) {
    union { uint32_t i; float f; } v; v.i = ((uint32_t)u) << 16; return v.f;
}

// ---------------- pass 0: fp32 node_states -> bf16 table (gather source) ----
__global__ __launch_bounds__(256) void k_cast(const float* __restrict__ ns,
                                              unsigned short* __restrict__ ns16) {
    int idx = blockIdx.x * blockDim.x + threadIdx.x;   // one ushort8 per thread
    if (idx >= N_NODES * HDIM / 8) return;
    const float4v* nsv = (const float4v*)ns;
    float4v v0 = nsv[idx * 2], v1 = nsv[idx * 2 + 1];
    ushort8 o;
    o[0] = f2bf(v0[0]); o[1] = f2bf(v0[1]); o[2] = f2bf(v0[2]); o[3] = f2bf(v0[3]);
    o[4] = f2bf(v1[0]); o[5] = f2bf(v1[1]); o[6] = f2bf(v1[2]); o[7] = f2bf(v1[3]);
    *(ushort8*)&ns16[(size_t)idx * 8] = o;
}

// ---------------- pass 1: count edges per (dst, rel) segment ----------------
__global__ void k_count(const int* __restrict__ ei, const int* __restrict__ et,
                        int* __restrict__ cnt) {
    int e = blockIdx.x * blockDim.x + threadIdx.x;
    if (e >= N_EDGES) return;
    int dst = ei[N_EDGES + e];
    int rel = et[e];
    atomicAdd(&cnt[dst * NREL + rel], 1);
}

// ---------------- pass 2a: per-chunk sums (coalesced int4) ------------------
__global__ __launch_bounds__(256) void k_scan1(const int* __restrict__ cnt,
                                               int* __restrict__ bsum) {
    int b = blockIdx.x, t = threadIdx.x;
    int idx = b * SCAN_CHUNK + t * 4;
    int4 v = {0, 0, 0, 0};
    if (idx + 3 < NSEG) v = *(const int4*)&cnt[idx];
    else {
        #pragma unroll
        for (int j = 0; j < 4; ++j) if (idx + j < NSEG) ((int*)&v)[j] = cnt[idx + j];
    }
    int s = v.x + v.y + v.z + v.w;
    #pragma unroll
    for (int o = 32; o > 0; o >>= 1) s += __shfl_xor(s, o, 64);
    __shared__ int ls[4];
    if ((t & 63) == 0) ls[t >> 6] = s;
    __syncthreads();
    if (t == 0) bsum[b] = ls[0] + ls[1] + ls[2] + ls[3];
}

// ---------------- pass 2b: scan the 391 block sums (1 tiny block) -----------
__global__ __launch_bounds__(512) void k_scan2(const int* __restrict__ bsum,
                                               int* __restrict__ boff) {
    __shared__ int s[512];
    int t = threadIdx.x;
    int v = (t < SCAN_NB) ? bsum[t] : 0;
    s[t] = v;
    __syncthreads();
    for (int d = 1; d < 512; d <<= 1) {
        int x = (t >= d) ? s[t - d] : 0;
        __syncthreads();
        s[t] += x;
        __syncthreads();
    }
    if (t < SCAN_NB) boff[t] = s[t] - v;  // exclusive prefix of block sums
}

// ---------------- pass 2c: in-chunk exclusive scan + block offset -----------
__global__ __launch_bounds__(256) void k_scan3(const int* __restrict__ cnt,
                                               const int* __restrict__ boff,
                                               int* __restrict__ off) {
    int b = blockIdx.x, t = threadIdx.x;
    int idx = b * SCAN_CHUNK + t * 4;
    int4 v = {0, 0, 0, 0};
    if (idx + 3 < NSEG) v = *(const int4*)&cnt[idx];
    else {
        #pragma unroll
        for (int j = 0; j < 4; ++j) if (idx + j < NSEG) ((int*)&v)[j] = cnt[idx + j];
    }
    int s = v.x + v.y + v.z + v.w;
    __shared__ int ls[256];
    ls[t] = s;
    __syncthreads();
    for (int d = 1; d < 256; d <<= 1) {
        int x = (t >= d) ? ls[t - d] : 0;
        __syncthreads();
        ls[t] += x;
        __syncthreads();
    }
    int run = boff[b] + ls[t] - s;  // exclusive prefix for this thread's 4 elems
    int4 w;
    w.x = run; run += v.x;
    w.y = run; run += v.y;
    w.z = run; run += v.z;
    w.w = run;
    if (idx + 3 < NSEG) *(int4*)&off[idx] = w;
    else {
        #pragma unroll
        for (int j = 0; j < 4; ++j) if (idx + j < NSEG) off[idx + j] = ((int*)&w)[j];
    }
    if (b == 0 && t == 0) off[NSEG] = N_EDGES;  // total count is exactly E
}

// ---------------- pass 3: scatter edge srcs into segment-sorted order -------
__global__ void k_scatter(const int* __restrict__ ei, const int* __restrict__ et,
                          const int* __restrict__ off, int* __restrict__ cursor,
                          int* __restrict__ srcs) {
    int e = blockIdx.x * blockDim.x + threadIdx.x;
    if (e >= N_EDGES) return;
    int src = ei[e];
    int dst = ei[N_EDGES + e];
    int rel = et[e];
    int seg = dst * NREL + rel;
    int pos = off[seg] + atomicAdd(&cursor[seg], 1);
    srcs[pos] = src;
}

// ---------------- pass 4: per-(node,rel) mean -> bf16 A matrix --------------
// XCD slice-locality: block (slice s, chunk c) gathers ONLY cols s*32..s*32+31
// (64B) of each source row. With linear-id round-robin dispatch, all slice-s
// blocks land on XCD s -> its L2 only touches the 3.2MB column-slice of ns16
// (fits 4MB) instead of streaming the whole 25.6MB table. 64 engines/block;
// engine = (node,rel) = 4 lanes x ushort8 (64B/edge). Afull rows padded to
// KDIM (4608B stride, non-power-of-2; root cols never written -- GEMM stages
// them from ns16).
__global__ __launch_bounds__(256) void k_aggregate(const unsigned short* __restrict__ ns16,
                                                   const int* __restrict__ off,
                                                   const int* __restrict__ srcs,
                                                   unsigned short* __restrict__ Afull) {
    int s   = blockIdx.x;              // slice 0..7 -> XCD s (heuristic)
    int n0  = blockIdx.y * AG_NPB;
    int tid = threadIdx.x;
    int eid = tid >> 2;                // 64 engines
    int l4  = tid & 3;                 // lane within engine
    int rel = eid & 7;
    int nodeoff = eid >> 3;            // 0..7
    int colbase = s * 32 + l4 * 8;     // 8 cols (16B) per lane

    for (int np = 0; np < AG_NPB; np += 8) {
        int n = n0 + np + nodeoff;
        if (n < N_NODES) {
            int seg = n * NREL + rel;
            int e0 = off[seg], e1 = off[seg + 1];
            int cnt = e1 - e0;
            int cs = cnt < 4 ? cnt : 4;
            int my_src = (l4 < cs) ? srcs[e0 + l4] : 0;

            float acc[8] = {0.f, 0.f, 0.f, 0.f, 0.f, 0.f, 0.f, 0.f};
            for (int k = 0; k < cs; ++k) {
                int src = __shfl(my_src, k, 4);
                ushort8 v = *(const ushort8*)&ns16[(size_t)src * HDIM + colbase];
                #pragma unroll
                for (int j = 0; j < 8; ++j) acc[j] += bf2f(v[j]);
            }
            for (int e = e0 + 4; e < e1; ++e) {     // tail beyond 4 edges
                int src = srcs[e];
                ushort8 v = *(const ushort8*)&ns16[(size_t)src * HDIM + colbase];
                #pragma unroll
                for (int j = 0; j < 8; ++j) acc[j] += bf2f(v[j]);
            }
            float inv = (cnt > 0) ? 1.0f / (float)cnt : 0.0f;  // zero-edge -> 0
            ushort8 wv;
            #pragma unroll
            for (int j = 0; j < 8; ++j) wv[j] = f2bf(acc[j] * inv);
            *(ushort8*)&Afull[(size_t)n * KDIM + rel * HDIM + colbase] = wv;
        }
    }
}

// ---------------- pass 5: build transposed bf16 weight matrix (coalesced) ---
// 64x64 LDS-transpose tiles; LDS row stride 66 ushorts (odd dwords) -> free.
__global__ __launch_bounds__(256) void k_buildB(const float* __restrict__ Wrel,
                                                const float* __restrict__ Wroot,
                                                unsigned short* __restrict__ Bt) {
    __shared__ unsigned short tile[64][66];
    int k0 = blockIdx.x * 64;          // 36 k-tiles
    int j0 = blockIdx.y * 64;          // 4  j-tiles
    int t = threadIdx.x;

    #pragma unroll
    for (int p = 0; p < 16; ++p) {
        int idx = p * 256 + t;
        int kk = idx >> 6, jj = idx & 63;
        int k = k0 + kk;
        float v;
        if (k < NREL * HDIM) {
            int r = k >> 8, h = k & 255;
            v = Wrel[((size_t)r * HDIM + h) * HDIM + (j0 + jj)];
        } else {
            int h = k - NREL * HDIM;
            v = Wroot[(size_t)h * HDIM + (j0 + jj)];
        }
        tile[kk][jj] = f2bf(v);
    }
    __syncthreads();
    #pragma unroll
    for (int p = 0; p < 16; ++p) {
        int idx = p * 256 + t;
        int jj = idx >> 6, kk = idx & 63;
        Bt[(size_t)(j0 + jj) * KDIM + (k0 + kk)] = tile[kk][jj];
    }
}

// ---------------- pass 6: fused GEMM + bias + GELU + residual + LayerNorm ---
// Round-11 proven geometry (113us): BM=128/BN=256/BK=64, 512 threads, 8 waves
// 2x4, wave tile 64x64, zero-conflict slot^(row&7) swizzle both-sides.
// Afull rows are KDIM wide (4608B stride -- non-power-of-2, avoids the L2
// channel camping that 4096B caused in rounds 12/13). Root K-iters (kt>=KA)
// stage A directly from ns16 (bit-identical).
#define BM 128
#define BN 256
#define BK 64
#define NITER (KDIM / BK)   // 36

__global__ __launch_bounds__(512, 4) void k_gemm(const unsigned short* __restrict__ A,
                                                 const unsigned short* __restrict__ ns16,
                                                 const unsigned short* __restrict__ Bt,
                                                 const float* __restrict__ ns,
                                                 const float* __restrict__ bias,
                                                 const float* __restrict__ gamma,
                                                 const float* __restrict__ beta,
                                                 float* __restrict__ out, int M) {
    __shared__ __align__(16) unsigned short As[BM * BK];   // 16 KB, row = 128 B
    __shared__ __align__(16) unsigned short Bs[BN * BK];   // 32 KB, row = 128 B
    __shared__ float s1buf[BM][4], s2buf[BM][4];           // 4 KB LN partials

    int tid  = threadIdx.x;
    int lane = tid & 63;
    int wid  = tid >> 6;                  // 8 waves
    int wm   = wid >> 2, wn = wid & 3;    // 2x4 waves; wave tile = 64 rows x 64 cols
    int brow = blockIdx.x * BM;

    float4v acc[4][4] = {};

    const char* Ab = (const char*)A;
    const char* Nb = (const char*)ns16;
    const char* Bb = (const char*)Bt;
    const size_t rstride = (size_t)KDIM * 2;   // 4608 B row stride (A and Bt)

    for (int kt = 0; kt < KDIM; kt += BK) {
        // ---- stage A (2 passes) + B (4 passes); LDS linear, source pre-swizzled
        #pragma unroll
        for (int i = 0; i < 2; ++i) {
            int linear = i * 8192 + tid * 16;          // byte offset in As
            int row  = linear >> 7;                    // 128 B per row
            int slot = (linear >> 4) & 7;
            int kb   = (slot ^ (row & 7)) * 16;        // pre-swizzled source k-byte
            int ra = brow + row; if (ra > M - 1) ra = M - 1;
            const char* ga = (kt < KA)
                ? Ab + (size_t)ra * rstride + (size_t)(kt * 2 + kb)
                : Nb + (size_t)ra * (HDIM * 2) + (size_t)((kt - KA) * 2 + kb);
            __builtin_amdgcn_global_load_lds(
                (const __attribute__((address_space(1))) void*)ga,
                (__attribute__((address_space(3))) void*)((char*)As + linear),
                16, 0, 0);
        }
        #pragma unroll
        for (int i = 0; i < 4; ++i) {
            int linear = i * 8192 + tid * 16;          // byte offset in Bs
            int row  = linear >> 7;                    // output col 0..255
            int slot = (linear >> 4) & 7;
            int kb   = (slot ^ (row & 7)) * 16;
            const char* gb = Bb + (size_t)row * rstride + (size_t)(kt * 2 + kb);
            __builtin_amdgcn_global_load_lds(
                (const __attribute__((address_space(1))) void*)gb,
                (__attribute__((address_space(3))) void*)((char*)Bs + linear),
                16, 0, 0);
        }
        __syncthreads();

        // ---- LDS -> fragments (swizzled read) -> MFMA ----
        #pragma unroll
        for (int h = 0; h < 2; ++h) {                  // two K=32 halves
            short8 a[4], b[4];
            int s0 = h * 4 + (lane >> 4);
            #pragma unroll
            for (int m = 0; m < 4; ++m) {
                int r = wm * 64 + m * 16 + (lane & 15);
                a[m] = *(const short8*)((const char*)As + r * 128 + ((s0 ^ (r & 7)) * 16));
            }
            #pragma unroll
            for (int n = 0; n < 4; ++n) {
                int r = wn * 64 + n * 16 + (lane & 15);
                b[n] = *(const short8*)((const char*)Bs + r * 128 + ((s0 ^ (r & 7)) * 16));
            }
            #pragma unroll
            for (int m = 0; m < 4; ++m)
                #pragma unroll
                for (int n = 0; n < 4; ++n)
                    acc[m][n] = __builtin_amdgcn_mfma_f32_16x16x32_bf16(a[m], b[n], acc[m][n], 0, 0, 0);
        }
        __syncthreads();
    }

    // ---- fused epilogue -----------------------------------------------------
    int cols[4];
    float bias_v[4];
    #pragma unroll
    for (int n = 0; n < 4; ++n) {
        cols[n] = wn * 64 + n * 16 + (lane & 15);
        bias_v[n] = bias[cols[n]];
    }

    // bias + exact GELU + residual; acc overwritten with x; LN partials to LDS
    #pragma unroll
    for (int m = 0; m < 4; ++m) {
        #pragma unroll
        for (int q = 0; q < 4; ++q) {
            int lr = wm * 64 + m * 16 + (lane >> 4) * 4 + q;
            int r  = brow + lr;
            float s1 = 0.f, s2 = 0.f;
            #pragma unroll
            for (int n = 0; n < 4; ++n) {
                float conv = acc[m][n][q] + bias_v[n];
                float g = 0.5f * conv * (1.0f + erff(conv * 0.70710678118654752f));
                float resid = (r < M) ? ns[(size_t)r * HDIM + cols[n]] : 0.f;
                float x = g + resid;
                acc[m][n][q] = x;
                s1 += x; s2 += x * x;
            }
            #pragma unroll
            for (int o = 8; o > 0; o >>= 1) {   // reduce across the 16 col-lanes
                s1 += __shfl_xor(s1, o, 64);
                s2 += __shfl_xor(s2, o, 64);
            }
            if ((lane & 15) == 0) { s1buf[lr][wn] = s1; s2buf[lr][wn] = s2; }
        }
    }
    __syncthreads();

    float gam[4], bet[4];
    #pragma unroll
    for (int n = 0; n < 4; ++n) { gam[n] = gamma[cols[n]]; bet[n] = beta[cols[n]]; }

    #pragma unroll
    for (int m = 0; m < 4; ++m) {
        #pragma unroll
        for (int q = 0; q < 4; ++q) {
            int lr = wm * 64 + m * 16 + (lane >> 4) * 4 + q;
            int r  = brow + lr;
            float t1 = s1buf[lr][0] + s1buf[lr][1] + s1buf[lr][2] + s1buf[lr][3];
            float t2 = s2buf[lr][0] + s2buf[lr][1] + s2buf[lr][2] + s2buf[lr][3];
            float mu  = t1 * (1.0f / HDIM);
            float var = t2 * (1.0f / HDIM) - mu * mu;
            float rstd = rsqrtf(var + LN_EPSF);
            if (r < M) {
                #pragma unroll
                for (int n = 0; n < 4; ++n) {
                    float x = acc[m][n][q];
                    out[(size_t)r * HDIM + cols[n]] = gam[n] * (x - mu) * rstd + bet[n];
                }
            }
        }
    }
}

extern "C" void kernel_launch(void* const* d_in, const int* in_sizes, int n_in,
                              void* d_out, int out_size, void* d_ws, size_t ws_size,
                              hipStream_t stream) {
    const float* ns    = (const float*)d_in[0];
    const int*   ei    = (const int*)d_in[1];   // [2, E] : src row then dst row
    const int*   et    = (const int*)d_in[2];   // [E]
    const float* Wrel  = (const float*)d_in[3]; // [R, H, H]
    const float* Wroot = (const float*)d_in[4]; // [H, H]
    const float* bias  = (const float*)d_in[5];
    const float* gamma = (const float*)d_in[6];
    const float* beta  = (const float*)d_in[7];
    float* out = (float*)d_out;

    char* w = (char*)d_ws;
    auto take = [&](size_t bytes) -> char* {
        char* p = w; w += (bytes + 255) & ~(size_t)255; return p;
    };
    int* cnt              = (int*)take((size_t)NSEG * 4);
    int* segoff           = (int*)take((size_t)(NSEG + 1) * 4);
    int* cursor           = (int*)take((size_t)NSEG * 4);
    int* srcs             = (int*)take((size_t)N_EDGES * 4);
    int* bsum             = (int*)take((size_t)SCAN_NB * 4);
    int* boff             = (int*)take((size_t)SCAN_NB * 4);
    unsigned short* Afull = (unsigned short*)take((size_t)N_NODES * KDIM * 2);
    unsigned short* Bt    = (unsigned short*)take((size_t)HDIM * KDIM * 2);
    unsigned short* ns16  = (unsigned short*)take((size_t)N_NODES * HDIM * 2);

    hipMemsetAsync(cnt, 0, (size_t)NSEG * 4, stream);
    hipMemsetAsync(cursor, 0, (size_t)NSEG * 4, stream);

    k_cast<<<(N_NODES * HDIM / 8 + 255) / 256, 256, 0, stream>>>(ns, ns16);
    k_count<<<(N_EDGES + 255) / 256, 256, 0, stream>>>(ei, et, cnt);
    k_scan1<<<SCAN_NB, 256, 0, stream>>>(cnt, bsum);
    k_scan2<<<1, 512, 0, stream>>>(bsum, boff);
    k_scan3<<<SCAN_NB, 256, 0, stream>>>(cnt, boff, segoff);
    k_scatter<<<(N_EDGES + 255) / 256, 256, 0, stream>>>(ei, et, segoff, cursor, srcs);

    dim3 ga(AG_SLICES, (N_NODES + AG_NPB - 1) / AG_NPB);   // (8, 196)
    k_aggregate<<<ga, 256, 0, stream>>>(ns16, segoff, srcs, Afull);

    dim3 gb(KDIM / 64, HDIM / 64);
    k_buildB<<<gb, 256, 0, stream>>>(Wrel, Wroot, Bt);

    dim3 gg((N_NODES + BM - 1) / BM, 1);
    k_gemm<<<gg, 512, 0, stream>>>(Afull, ns16, Bt, ns, bias, gamma, beta, out, N_NODES);
}

// Round 15
// 304.148 us; speedup vs baseline: 1.1403x; 1.1403x over previous
//
#include <hip/hip_runtime.h>
#include <cstdint>
#include <cstddef>

#define N_NODES 50000
#define N_EDGES 800000
#define HDIM    256
#define NREL    8
#define NSEG    (N_NODES * NREL)      // 400000
#define KDIM    (NREL * HDIM + HDIM)  // 2304 GEMM K: [mean slices | node_states]
#define KA      (NREL * HDIM)         // 2048 cols with aggregated data
#define LN_EPSF 1e-5f

#define SCAN_CHUNK 1024
#define SCAN_NB    ((NSEG + SCAN_CHUNK - 1) / SCAN_CHUNK)   // 391

using short8  = __attribute__((ext_vector_type(8))) short;
using ushort8 = __attribute__((ext_vector_type(8))) unsigned short;
using float4v = __attribute__((ext_vector_type(4))) float;

static __device__ __forceinline__ unsigned short f2bf(float f) {
    union { float f; uint32_t i; } v; v.f = f;
    uint32_t r = v.i + 0x7FFFu + ((v.i >> 16) & 1u);   // round-to-nearest-even
    return (unsigned short)(r >> 16);
}
static __device__ __forceinline__ float bf2f(unsigned short u) {
    union { uint32_t i; float f; } v; v.i = ((uint32_t)u) << 16; return v.f;
}

// ---------------- pass 0: fp32 node_states -> bf16 table (gather source) ----
__global__ __launch_bounds__(256) void k_cast(const float* __restrict__ ns,
                                              unsigned short* __restrict__ ns16) {
    int idx = blockIdx.x * blockDim.x + threadIdx.x;   // one ushort8 per thread
    if (idx >= N_NODES * HDIM / 8) return;
    const float4v* nsv = (const float4v*)ns;
    float4v v0 = nsv[idx * 2], v1 = nsv[idx * 2 + 1];
    ushort8 o;
    o[0] = f2bf(v0[0]); o[1] = f2bf(v0[1]); o[2] = f2bf(v0[2]); o[3] = f2bf(v0[3]);
    o[4] = f2bf(v1[0]); o[5] = f2bf(v1[1]); o[6] = f2bf(v1[2]); o[7] = f2bf(v1[3]);
    *(ushort8*)&ns16[(size_t)idx * 8] = o;
}

// ---------------- pass 1: count edges per (dst, rel) segment ----------------
__global__ void k_count(const int* __restrict__ ei, const int* __restrict__ et,
                        int* __restrict__ cnt) {
    int e = blockIdx.x * blockDim.x + threadIdx.x;
    if (e >= N_EDGES) return;
    int dst = ei[N_EDGES + e];
    int rel = et[e];
    atomicAdd(&cnt[dst * NREL + rel], 1);
}

// ---------------- pass 2a: per-chunk sums (coalesced int4) ------------------
__global__ __launch_bounds__(256) void k_scan1(const int* __restrict__ cnt,
                                               int* __restrict__ bsum) {
    int b = blockIdx.x, t = threadIdx.x;
    int idx = b * SCAN_CHUNK + t * 4;
    int4 v = {0, 0, 0, 0};
    if (idx + 3 < NSEG) v = *(const int4*)&cnt[idx];
    else {
        #pragma unroll
        for (int j = 0; j < 4; ++j) if (idx + j < NSEG) ((int*)&v)[j] = cnt[idx + j];
    }
    int s = v.x + v.y + v.z + v.w;
    #pragma unroll
    for (int o = 32; o > 0; o >>= 1) s += __shfl_xor(s, o, 64);
    __shared__ int ls[4];
    if ((t & 63) == 0) ls[t >> 6] = s;
    __syncthreads();
    if (t == 0) bsum[b] = ls[0] + ls[1] + ls[2] + ls[3];
}

// ---------------- pass 2b: scan the 391 block sums (1 tiny block) -----------
__global__ __launch_bounds__(512) void k_scan2(const int* __restrict__ bsum,
                                               int* __restrict__ boff) {
    __shared__ int s[512];
    int t = threadIdx.x;
    int v = (t < SCAN_NB) ? bsum[t] : 0;
    s[t] = v;
    __syncthreads();
    for (int d = 1; d < 512; d <<= 1) {
        int x = (t >= d) ? s[t - d] : 0;
        __syncthreads();
        s[t] += x;
        __syncthreads();
    }
    if (t < SCAN_NB) boff[t] = s[t] - v;  // exclusive prefix of block sums
}

// ---------------- pass 2c: in-chunk exclusive scan + block offset -----------
__global__ __launch_bounds__(256) void k_scan3(const int* __restrict__ cnt,
                                               const int* __restrict__ boff,
                                               int* __restrict__ off) {
    int b = blockIdx.x, t = threadIdx.x;
    int idx = b * SCAN_CHUNK + t * 4;
    int4 v = {0, 0, 0, 0};
    if (idx + 3 < NSEG) v = *(const int4*)&cnt[idx];
    else {
        #pragma unroll
        for (int j = 0; j < 4; ++j) if (idx + j < NSEG) ((int*)&v)[j] = cnt[idx + j];
    }
    int s = v.x + v.y + v.z + v.w;
    __shared__ int ls[256];
    ls[t] = s;
    __syncthreads();
    for (int d = 1; d < 256; d <<= 1) {
        int x = (t >= d) ? ls[t - d] : 0;
        __syncthreads();
        ls[t] += x;
        __syncthreads();
    }
    int run = boff[b] + ls[t] - s;  // exclusive prefix for this thread's 4 elems
    int4 w;
    w.x = run; run += v.x;
    w.y = run; run += v.y;
    w.z = run; run += v.z;
    w.w = run;
    if (idx + 3 < NSEG) *(int4*)&off[idx] = w;
    else {
        #pragma unroll
        for (int j = 0; j < 4; ++j) if (idx + j < NSEG) off[idx + j] = ((int*)&w)[j];
    }
    if (b == 0 && t == 0) off[NSEG] = N_EDGES;  // total count is exactly E
}

// ---------------- pass 3: scatter edge srcs into segment-sorted order -------
__global__ void k_scatter(const int* __restrict__ ei, const int* __restrict__ et,
                          const int* __restrict__ off, int* __restrict__ cursor,
                          int* __restrict__ srcs) {
    int e = blockIdx.x * blockDim.x + threadIdx.x;
    if (e >= N_EDGES) return;
    int src = ei[e];
    int dst = ei[N_EDGES + e];
    int rel = et[e];
    int seg = dst * NREL + rel;
    int pos = off[seg] + atomicAdd(&cursor[seg], 1);
    srcs[pos] = src;
}

// ---------------- pass 4: per-(node,rel) mean -> bf16 A matrix --------------
// Round-11 proven structure (~100us, at the per-XCD-stream + write floor):
// 8 relation-groups x 32 lanes; lane owns 8 h-values = ONE ushort8 (16B) per
// edge; fp32 accumulate; register-broadcast src indices. Writes only the
// KA=2048 aggregated cols; rows are KDIM wide (4608B stride, non-pow2 --
// 4096B caused L2 channel camping in the GEMM, rounds 12/13).
__global__ __launch_bounds__(256) void k_aggregate(const unsigned short* __restrict__ ns16,
                                                   const int* __restrict__ off,
                                                   const int* __restrict__ srcs,
                                                   unsigned short* __restrict__ Afull) {
    int n = blockIdx.x, t = threadIdx.x;
    int g = t >> 5;          // relation 0..7
    int i = t & 31;          // h-slice: h = i*8 .. i*8+7
    int seg = n * NREL + g;
    int e0 = off[seg], e1 = off[seg + 1];
    int cnt = e1 - e0;
    int cs = cnt < 32 ? cnt : 32;
    int my_src = (i < cs) ? srcs[e0 + i] : 0;

    const ushort8* nsv = (const ushort8*)ns16;   // 32 ushort8 per row
    float acc[8] = {0.f, 0.f, 0.f, 0.f, 0.f, 0.f, 0.f, 0.f};

    for (int k = 0; k < cs; ++k) {
        int src = __shfl(my_src, k, 32);
        ushort8 v = nsv[(size_t)src * 32 + i];
        #pragma unroll
        for (int j = 0; j < 8; ++j) acc[j] += bf2f(v[j]);
    }
    for (int e = e0 + 32; e < e1; ++e) {       // tail beyond 32 edges (rare)
        int src = srcs[e];
        ushort8 v = nsv[(size_t)src * 32 + i];
        #pragma unroll
        for (int j = 0; j < 8; ++j) acc[j] += bf2f(v[j]);
    }

    float inv = (cnt > 0) ? 1.0f / (float)cnt : 0.0f;  // zero-edge buckets stay 0
    ushort8 wv;
    #pragma unroll
    for (int j = 0; j < 8; ++j) wv[j] = f2bf(acc[j] * inv);
    *(ushort8*)&Afull[(size_t)n * KDIM + g * HDIM + i * 8] = wv;
}

// ---------------- pass 5: build transposed bf16 weight matrix (coalesced) ---
// 64x64 LDS-transpose tiles; LDS row stride 66 ushorts (odd dwords) -> free.
__global__ __launch_bounds__(256) void k_buildB(const float* __restrict__ Wrel,
                                                const float* __restrict__ Wroot,
                                                unsigned short* __restrict__ Bt) {
    __shared__ unsigned short tile[64][66];
    int k0 = blockIdx.x * 64;          // 36 k-tiles
    int j0 = blockIdx.y * 64;          // 4  j-tiles
    int t = threadIdx.x;

    #pragma unroll
    for (int p = 0; p < 16; ++p) {
        int idx = p * 256 + t;
        int kk = idx >> 6, jj = idx & 63;
        int k = k0 + kk;
        float v;
        if (k < NREL * HDIM) {
            int r = k >> 8, h = k & 255;
            v = Wrel[((size_t)r * HDIM + h) * HDIM + (j0 + jj)];
        } else {
            int h = k - NREL * HDIM;
            v = Wroot[(size_t)h * HDIM + (j0 + jj)];
        }
        tile[kk][jj] = f2bf(v);
    }
    __syncthreads();
    #pragma unroll
    for (int p = 0; p < 16; ++p) {
        int idx = p * 256 + t;
        int jj = idx >> 6, kk = idx & 63;
        Bt[(size_t)(j0 + jj) * KDIM + (k0 + kk)] = tile[kk][jj];
    }
}

// ---------------- pass 6: fused GEMM + bias + GELU + residual + LayerNorm ---
// Round-11 proven geometry (113us): BM=128/BN=256/BK=64, 512 threads, 8 waves
// 2x4, wave tile 64x64, zero-conflict slot^(row&7) swizzle both-sides.
// Root K-iters (kt>=KA) stage A directly from ns16 (bit-identical values).
#define BM 128
#define BN 256
#define BK 64
#define NITER (KDIM / BK)   // 36

__global__ __launch_bounds__(512, 4) void k_gemm(const unsigned short* __restrict__ A,
                                                 const unsigned short* __restrict__ ns16,
                                                 const unsigned short* __restrict__ Bt,
                                                 const float* __restrict__ ns,
                                                 const float* __restrict__ bias,
                                                 const float* __restrict__ gamma,
                                                 const float* __restrict__ beta,
                                                 float* __restrict__ out, int M) {
    __shared__ __align__(16) unsigned short As[BM * BK];   // 16 KB, row = 128 B
    __shared__ __align__(16) unsigned short Bs[BN * BK];   // 32 KB, row = 128 B
    __shared__ float s1buf[BM][4], s2buf[BM][4];           // 4 KB LN partials

    int tid  = threadIdx.x;
    int lane = tid & 63;
    int wid  = tid >> 6;                  // 8 waves
    int wm   = wid >> 2, wn = wid & 3;    // 2x4 waves; wave tile = 64 rows x 64 cols
    int brow = blockIdx.x * BM;

    float4v acc[4][4] = {};

    const char* Ab = (const char*)A;
    const char* Nb = (const char*)ns16;
    const char* Bb = (const char*)Bt;
    const size_t rstride = (size_t)KDIM * 2;   // 4608 B row stride (A and Bt)

    for (int kt = 0; kt < KDIM; kt += BK) {
        // ---- stage A (2 passes) + B (4 passes); LDS linear, source pre-swizzled
        #pragma unroll
        for (int i = 0; i < 2; ++i) {
            int linear = i * 8192 + tid * 16;          // byte offset in As
            int row  = linear >> 7;                    // 128 B per row
            int slot = (linear >> 4) & 7;
            int kb   = (slot ^ (row & 7)) * 16;        // pre-swizzled source k-byte
            int ra = brow + row; if (ra > M - 1) ra = M - 1;
            const char* ga = (kt < KA)
                ? Ab + (size_t)ra * rstride + (size_t)(kt * 2 + kb)
                : Nb + (size_t)ra * (HDIM * 2) + (size_t)((kt - KA) * 2 + kb);
            __builtin_amdgcn_global_load_lds(
                (const __attribute__((address_space(1))) void*)ga,
                (__attribute__((address_space(3))) void*)((char*)As + linear),
                16, 0, 0);
        }
        #pragma unroll
        for (int i = 0; i < 4; ++i) {
            int linear = i * 8192 + tid * 16;          // byte offset in Bs
            int row  = linear >> 7;                    // output col 0..255
            int slot = (linear >> 4) & 7;
            int kb   = (slot ^ (row & 7)) * 16;
            const char* gb = Bb + (size_t)row * rstride + (size_t)(kt * 2 + kb);
            __builtin_amdgcn_global_load_lds(
                (const __attribute__((address_space(1))) void*)gb,
                (__attribute__((address_space(3))) void*)((char*)Bs + linear),
                16, 0, 0);
        }
        __syncthreads();

        // ---- LDS -> fragments (swizzled read) -> MFMA ----
        #pragma unroll
        for (int h = 0; h < 2; ++h) {                  // two K=32 halves
            short8 a[4], b[4];
            int s0 = h * 4 + (lane >> 4);
            #pragma unroll
            for (int m = 0; m < 4; ++m) {
                int r = wm * 64 + m * 16 + (lane & 15);
                a[m] = *(const short8*)((const char*)As + r * 128 + ((s0 ^ (r & 7)) * 16));
            }
            #pragma unroll
            for (int n = 0; n < 4; ++n) {
                int r = wn * 64 + n * 16 + (lane & 15);
                b[n] = *(const short8*)((const char*)Bs + r * 128 + ((s0 ^ (r & 7)) * 16));
            }
            #pragma unroll
            for (int m = 0; m < 4; ++m)
                #pragma unroll
                for (int n = 0; n < 4; ++n)
                    acc[m][n] = __builtin_amdgcn_mfma_f32_16x16x32_bf16(a[m], b[n], acc[m][n], 0, 0, 0);
        }
        __syncthreads();
    }

    // ---- fused epilogue -----------------------------------------------------
    int cols[4];
    float bias_v[4];
    #pragma unroll
    for (int n = 0; n < 4; ++n) {
        cols[n] = wn * 64 + n * 16 + (lane & 15);
        bias_v[n] = bias[cols[n]];
    }

    // bias + exact GELU + residual; acc overwritten with x; LN partials to LDS
    #pragma unroll
    for (int m = 0; m < 4; ++m) {
        #pragma unroll
        for (int q = 0; q < 4; ++q) {
            int lr = wm * 64 + m * 16 + (lane >> 4) * 4 + q;
            int r  = brow + lr;
            float s1 = 0.f, s2 = 0.f;
            #pragma unroll
            for (int n = 0; n < 4; ++n) {
                float conv = acc[m][n][q] + bias_v[n];
                float g = 0.5f * conv * (1.0f + erff(conv * 0.70710678118654752f));
                float resid = (r < M) ? ns[(size_t)r * HDIM + cols[n]] : 0.f;
                float x = g + resid;
                acc[m][n][q] = x;
                s1 += x; s2 += x * x;
            }
            #pragma unroll
            for (int o = 8; o > 0; o >>= 1) {   // reduce across the 16 col-lanes
                s1 += __shfl_xor(s1, o, 64);
                s2 += __shfl_xor(s2, o, 64);
            }
            if ((lane & 15) == 0) { s1buf[lr][wn] = s1; s2buf[lr][wn] = s2; }
        }
    }
    __syncthreads();

    float gam[4], bet[4];
    #pragma unroll
    for (int n = 0; n < 4; ++n) { gam[n] = gamma[cols[n]]; bet[n] = beta[cols[n]]; }

    #pragma unroll
    for (int m = 0; m < 4; ++m) {
        #pragma unroll
        for (int q = 0; q < 4; ++q) {
            int lr = wm * 64 + m * 16 + (lane >> 4) * 4 + q;
            int r  = brow + lr;
            float t1 = s1buf[lr][0] + s1buf[lr][1] + s1buf[lr][2] + s1buf[lr][3];
            float t2 = s2buf[lr][0] + s2buf[lr][1] + s2buf[lr][2] + s2buf[lr][3];
            float mu  = t1 * (1.0f / HDIM);
            float var = t2 * (1.0f / HDIM) - mu * mu;
            float rstd = rsqrtf(var + LN_EPSF);
            if (r < M) {
                #pragma unroll
                for (int n = 0; n < 4; ++n) {
                    float x = acc[m][n][q];
                    out[(size_t)r * HDIM + cols[n]] = gam[n] * (x - mu) * rstd + bet[n];
                }
            }
        }
    }
}

extern "C" void kernel_launch(void* const* d_in, const int* in_sizes, int n_in,
                              void* d_out, int out_size, void* d_ws, size_t ws_size,
                              hipStream_t stream) {
    const float* ns    = (const float*)d_in[0];
    const int*   ei    = (const int*)d_in[1];   // [2, E] : src row then dst row
    const int*   et    = (const int*)d_in[2];   // [E]
    const float* Wrel  = (const float*)d_in[3]; // [R, H, H]
    const float* Wroot = (const float*)d_in[4]; // [H, H]
    const float* bias  = (const float*)d_in[5];
    const float* gamma = (const float*)d_in[6];
    const float* beta  = (const float*)d_in[7];
    float* out = (float*)d_out;

    char* w = (char*)d_ws;
    auto take = [&](size_t bytes) -> char* {
        char* p = w; w += (bytes + 255) & ~(size_t)255; return p;
    };
    int* cnt              = (int*)take((size_t)NSEG * 4);
    int* segoff           = (int*)take((size_t)(NSEG + 1) * 4);
    int* cursor           = (int*)take((size_t)NSEG * 4);
    int* srcs             = (int*)take((size_t)N_EDGES * 4);
    int* bsum             = (int*)take((size_t)SCAN_NB * 4);
    int* boff             = (int*)take((size_t)SCAN_NB * 4);
    unsigned short* Afull = (unsigned short*)take((size_t)N_NODES * KDIM * 2);
    unsigned short* Bt    = (unsigned short*)take((size_t)HDIM * KDIM * 2);
    unsigned short* ns16  = (unsigned short*)take((size_t)N_NODES * HDIM * 2);

    hipMemsetAsync(cnt, 0, (size_t)NSEG * 4, stream);
    hipMemsetAsync(cursor, 0, (size_t)NSEG * 4, stream);

    k_cast<<<(N_NODES * HDIM / 8 + 255) / 256, 256, 0, stream>>>(ns, ns16);
    k_count<<<(N_EDGES + 255) / 256, 256, 0, stream>>>(ei, et, cnt);
    k_scan1<<<SCAN_NB, 256, 0, stream>>>(cnt, bsum);
    k_scan2<<<1, 512, 0, stream>>>(bsum, boff);
    k_scan3<<<SCAN_NB, 256, 0, stream>>>(cnt, boff, segoff);
    k_scatter<<<(N_EDGES + 255) / 256, 256, 0, stream>>>(ei, et, segoff, cursor, srcs);
    k_aggregate<<<N_NODES, 256, 0, stream>>>(ns16, segoff, srcs, Afull);
    dim3 gb(KDIM / 64, HDIM / 64);
    k_buildB<<<gb, 256, 0, stream>>>(Wrel, Wroot, Bt);

    dim3 gg((N_NODES + BM - 1) / BM, 1);
    k_gemm<<<gg, 512, 0, stream>>>(Afull, ns16, Bt, ns, bias, gamma, beta, out, N_NODES);
}